// Round 10
// baseline (140.578 us; speedup 1.0000x reference)
//
#include <hip/hip_runtime.h>

// SIREN forward, MFMA, round 10: no output stage; direct D-fragment bypass
// stores; occupancy from resource diet (42 KB LDS, ~128 VGPR -> 12 waves/CU).
//
// Ladder: 1526 (f32 spill) -> 473 (MFMA chain) -> 326 (1KB-contiguous
// stores) -> 122.5 us (sc0 sc1 nt: L2 store-miss read-fill eliminated).
// r8 (weights in VGPR, same occupancy): neutral. r9 (launch_bounds(256,3)
// + 224 natural VGPR): kernel never ran -- output all zeros. Lesson: don't
// force waves/EU with launch_bounds on a register-heavy kernel.
//
// This round: r7 structure (weights in LDS, VGPR~128) but the 32 KB LDS
// transpose stage is DELETED. Rationale: the stage only existed to defeat
// the L2 fetch-on-write-miss, which sc0 sc1 already bypasses (r7). Direct
// D-fragment stores are 64-B-cluster aligned (lanes {p,p+16,p+32,p+48}
// write contiguous 64 B at out[point*128+16*mt]) = HBM atom granule.
// LDS 74.5 -> 42.3 KB => 3 blocks/CU naturally; no launch_bounds change.

typedef _Float16 half8 __attribute__((ext_vector_type(8)));
typedef float f32x4 __attribute__((ext_vector_type(4)));

#define OMEGA 5.0f

__global__ __launch_bounds__(256, 2) void siren_mfma_kernel(
    const float* __restrict__ coords,
    const float* __restrict__ W0, const float* __restrict__ b0,
    const float* __restrict__ W1, const float* __restrict__ b1,
    const float* __restrict__ W2, const float* __restrict__ b2,
    const float* __restrict__ W3, const float* __restrict__ b3,
    const float* __restrict__ W4, const float* __restrict__ b4,
    float* __restrict__ out, int n)
{
    // Pre-gathered A-fragment tables: [kblock][mtile][lane] -> 8 f16 (16 B).
    __shared__ half8 AT[3][2][4][64];    // hidden layers W1..W3: 24 KB
    __shared__ half8 AT4[2][8][64];      // W4: 16 KB
    __shared__ float4 w0tab[64];         // {5*W0[n][0], 5*W0[n][1], 5*b0[n], 0}
    __shared__ __align__(16) float btab[3][64];   // 5*b1..b3
    __shared__ __align__(16) float b4tab[128];    // 5*b4

    const int tid  = threadIdx.x;
    const int lane = tid & 63;
    const int g    = lane >> 4;        // lane group 0..3
    const int w    = tid >> 6;         // wave in block

    // ---------------- prep: build fragment tables (r7-identical) ----------------
    {
        const float* Wp[3] = {W1, W2, W3};
        #pragma unroll
        for (int L = 0; L < 3; ++L) {
            #pragma unroll
            for (int c = 0; c < 2; ++c) {
                int chunk = w + 4 * c;               // 0..7 = b*4 + mt
                int b  = chunk >> 2, mt = chunk & 3;
                const float* src = Wp[L] + (16 * mt + (lane & 15)) * 64 + 32 * b + 4 * g;
                float4 wa = *(const float4*)(src);
                float4 wb = *(const float4*)(src + 16);
                half8 h;
                h[0] = (_Float16)(OMEGA * wa.x); h[1] = (_Float16)(OMEGA * wa.y);
                h[2] = (_Float16)(OMEGA * wa.z); h[3] = (_Float16)(OMEGA * wa.w);
                h[4] = (_Float16)(OMEGA * wb.x); h[5] = (_Float16)(OMEGA * wb.y);
                h[6] = (_Float16)(OMEGA * wb.z); h[7] = (_Float16)(OMEGA * wb.w);
                AT[L][b][mt][lane] = h;
            }
        }
        #pragma unroll
        for (int c = 0; c < 4; ++c) {
            int chunk = w + 4 * c;                   // 0..15 = b*8 + mt
            int b  = chunk >> 3, mt = chunk & 7;
            const float* src = W4 + (16 * mt + (lane & 15)) * 64 + 32 * b + 4 * g;
            float4 wa = *(const float4*)(src);
            float4 wb = *(const float4*)(src + 16);
            half8 h;
            h[0] = (_Float16)(OMEGA * wa.x); h[1] = (_Float16)(OMEGA * wa.y);
            h[2] = (_Float16)(OMEGA * wa.z); h[3] = (_Float16)(OMEGA * wa.w);
            h[4] = (_Float16)(OMEGA * wb.x); h[5] = (_Float16)(OMEGA * wb.y);
            h[6] = (_Float16)(OMEGA * wb.z); h[7] = (_Float16)(OMEGA * wb.w);
            AT4[b][mt][lane] = h;
        }
        if (tid < 64) {
            w0tab[tid] = make_float4(OMEGA * W0[2 * tid], OMEGA * W0[2 * tid + 1],
                                     OMEGA * b0[tid], 0.f);
            btab[0][tid] = OMEGA * b1[tid];
            btab[1][tid] = OMEGA * b2[tid];
            btab[2][tid] = OMEGA * b3[tid];
        }
        if (tid < 128) b4tab[tid] = OMEGA * b4[tid];
    }
    __syncthreads();

    // ---------------- main loop: one wave = 16 points per batch ----------------
    const int p   = lane & 15;                // point-in-batch (= MFMA column)
    const int nb  = (n + 15) >> 4;
    const int wv  = blockIdx.x * 4 + w;
    const int nw  = gridDim.x * 4;

    for (int batch = wv; batch < nb; batch += nw) {
        int point = batch * 16 + p;
        int pt    = point < n ? point : n - 1;
        float2 c2 = *(const float2*)(coords + 2ull * (unsigned)pt);

        // Layer 0 (fp32 VALU): lane computes Z0[nrn][p] for nrn = 16t+4g+r,
        // landing directly in B-fragment slots: zb[t>>1][4*(t&1)+r].
        half8 zb[2];
        #pragma unroll
        for (int t = 0; t < 4; ++t) {
            #pragma unroll
            for (int r = 0; r < 4; ++r) {
                float4 ww = w0tab[16 * t + 4 * g + r];
                float z = __sinf(fmaf(c2.x, ww.x, fmaf(c2.y, ww.y, ww.z)));
                zb[t >> 1][4 * (t & 1) + r] = (_Float16)z;
            }
        }

        // Hidden layers 1..3
        #pragma unroll
        for (int L = 0; L < 3; ++L) {
            f32x4 acc[4];
            #pragma unroll
            for (int t = 0; t < 4; ++t) {
                float4 bv = *(const float4*)&btab[L][16 * t + 4 * g];
                acc[t][0] = bv.x; acc[t][1] = bv.y; acc[t][2] = bv.z; acc[t][3] = bv.w;
            }
            #pragma unroll
            for (int b = 0; b < 2; ++b) {
                #pragma unroll
                for (int mt = 0; mt < 4; ++mt) {
                    acc[mt] = __builtin_amdgcn_mfma_f32_16x16x32_f16(
                        AT[L][b][mt][lane], zb[b], acc[mt], 0, 0, 0);
                }
            }
            // activation + repack: D-regs -> next B-frags, all in-lane
            half8 zn[2];
            #pragma unroll
            for (int t = 0; t < 4; ++t) {
                #pragma unroll
                for (int r = 0; r < 4; ++r) {
                    zn[t >> 1][4 * (t & 1) + r] = (_Float16)__sinf(acc[t][r]);
                }
            }
            zb[0] = zn[0]; zb[1] = zn[1];
        }

        // Output layer: 64 -> 128. Direct D-fragment stores: lane's f32x4 is
        // 4 consecutive neurons of one point = contiguous 16 B; the 4 lanes
        // sharing p form one 64-B cluster at out[point*128 + 16*mt] (HBM
        // atom). sc0 sc1 nt bypasses L2 -> no read-for-ownership (r7).
        #pragma unroll
        for (int mt = 0; mt < 8; ++mt) {
            float4 bv = *(const float4*)&b4tab[16 * mt + 4 * g];
            f32x4 a4;
            a4[0] = bv.x; a4[1] = bv.y; a4[2] = bv.z; a4[3] = bv.w;
            a4 = __builtin_amdgcn_mfma_f32_16x16x32_f16(AT4[0][mt][lane], zb[0], a4, 0, 0, 0);
            a4 = __builtin_amdgcn_mfma_f32_16x16x32_f16(AT4[1][mt][lane], zb[1], a4, 0, 0, 0);
            f32x4 o;
            o[0] = __sinf(a4[0]); o[1] = __sinf(a4[1]);
            o[2] = __sinf(a4[2]); o[3] = __sinf(a4[3]);
            if (point < n) {
                float* gp = out + (size_t)point * 128 + 16 * mt + 4 * g;
                asm volatile("global_store_dwordx4 %0, %1, off sc0 sc1 nt"
                             :: "v"(gp), "v"(o) : "memory");
            }
        }
    }
}

extern "C" void kernel_launch(void* const* d_in, const int* in_sizes, int n_in,
                              void* d_out, int out_size, void* d_ws, size_t ws_size,
                              hipStream_t stream) {
    const float* coords = (const float*)d_in[0];
    const float* W0 = (const float*)d_in[1];
    const float* b0 = (const float*)d_in[2];
    const float* W1 = (const float*)d_in[3];
    const float* b1 = (const float*)d_in[4];
    const float* W2 = (const float*)d_in[5];
    const float* b2 = (const float*)d_in[6];
    const float* W3 = (const float*)d_in[7];
    const float* b3 = (const float*)d_in[8];
    const float* W4 = (const float*)d_in[9];
    const float* b4 = (const float*)d_in[10];
    float* out = (float*)d_out;

    int n = in_sizes[0] / 2;  // coords is (N, 2)
    int nb = (n + 15) / 16;
    int blocks = 768;         // 3 blocks/CU (42.3 KB LDS), 4 waves each
    int maxb = (nb + 3) / 4;
    if (blocks > maxb) blocks = maxb;
    hipLaunchKernelGGL(siren_mfma_kernel, dim3(blocks), dim3(256), 0, stream,
                       coords, W0, b0, W1, b1, W2, b2, W3, b3, W4, b4, out, n);
}

// Round 12
// 123.958 us; speedup vs baseline: 1.1341x; 1.1341x over previous
//
#include <hip/hip_runtime.h>

// SIREN forward, MFMA, round 12: r7 champion, store scope sc0+sc1 -> sc1.
//
// Ladder: 1526 -> 473 -> 326 -> 122.5 us (r7: 1KB-contiguous sc0 sc1 nt
// stores -- system-scope bypass kills the L2 store-miss read-fill).
// r8 (weights->VGPR): neutral. r9/r11 (launch shape changes): silent
// all-zeros failures -- launch_bounds/block-shape edits are high-risk on
// this stack; occupancy hypothesis shelved. r10 (no stage): scatter costs
// 15% even bypassed.
//
// This round, hypothesis (a): is the SYSTEM-scope store path the ~5.1 TB/s
// cap? Single token change vs r7: sc1-only (DEVICE scope). Device scope
// must still bypass the non-coherent per-XCD L2 (coherence point is the
// MALL/Infinity Cache), so the RFO fix should hold, but the write can ride
// the MALL path (fill kernel: 6.7 TB/s) instead of going straight to HBM.

typedef _Float16 half8 __attribute__((ext_vector_type(8)));
typedef float f32x4 __attribute__((ext_vector_type(4)));

#define OMEGA 5.0f

__global__ __launch_bounds__(256, 2) void siren_mfma_kernel(
    const float* __restrict__ coords,
    const float* __restrict__ W0, const float* __restrict__ b0,
    const float* __restrict__ W1, const float* __restrict__ b1,
    const float* __restrict__ W2, const float* __restrict__ b2,
    const float* __restrict__ W3, const float* __restrict__ b3,
    const float* __restrict__ W4, const float* __restrict__ b4,
    float* __restrict__ out, int n)
{
    // Pre-gathered A-fragment tables: [kblock][mtile][lane] -> 8 f16 (16 B).
    __shared__ half8 AT[3][2][4][64];    // hidden layers W1..W3: 24 KB
    __shared__ half8 AT4[2][8][64];      // W4: 16 KB
    __shared__ float4 w0tab[64];         // {5*W0[n][0], 5*W0[n][1], 5*b0[n], 0}
    __shared__ __align__(16) float btab[3][64];   // 5*b1..b3
    __shared__ __align__(16) float b4tab[128];    // 5*b4
    // Per-wave output slab: 16 points x 128 cols f32 (8 KB/wave, 32 KB).
    // float4-chunk XOR swizzle (chunk ^= row&7): 0 bank conflicts (r5 PMC).
    __shared__ float stage[4][16][128];

    const int tid  = threadIdx.x;
    const int lane = tid & 63;
    const int g    = lane >> 4;        // lane group 0..3
    const int w    = tid >> 6;         // wave in block

    // ---------------- prep: build fragment tables ----------------
    {
        const float* Wp[3] = {W1, W2, W3};
        #pragma unroll
        for (int L = 0; L < 3; ++L) {
            #pragma unroll
            for (int c = 0; c < 2; ++c) {
                int chunk = w + 4 * c;               // 0..7 = b*4 + mt
                int b  = chunk >> 2, mt = chunk & 3;
                const float* src = Wp[L] + (16 * mt + (lane & 15)) * 64 + 32 * b + 4 * g;
                float4 wa = *(const float4*)(src);
                float4 wb = *(const float4*)(src + 16);
                half8 h;
                h[0] = (_Float16)(OMEGA * wa.x); h[1] = (_Float16)(OMEGA * wa.y);
                h[2] = (_Float16)(OMEGA * wa.z); h[3] = (_Float16)(OMEGA * wa.w);
                h[4] = (_Float16)(OMEGA * wb.x); h[5] = (_Float16)(OMEGA * wb.y);
                h[6] = (_Float16)(OMEGA * wb.z); h[7] = (_Float16)(OMEGA * wb.w);
                AT[L][b][mt][lane] = h;
            }
        }
        #pragma unroll
        for (int c = 0; c < 4; ++c) {
            int chunk = w + 4 * c;                   // 0..15 = b*8 + mt
            int b  = chunk >> 3, mt = chunk & 7;
            const float* src = W4 + (16 * mt + (lane & 15)) * 64 + 32 * b + 4 * g;
            float4 wa = *(const float4*)(src);
            float4 wb = *(const float4*)(src + 16);
            half8 h;
            h[0] = (_Float16)(OMEGA * wa.x); h[1] = (_Float16)(OMEGA * wa.y);
            h[2] = (_Float16)(OMEGA * wa.z); h[3] = (_Float16)(OMEGA * wa.w);
            h[4] = (_Float16)(OMEGA * wb.x); h[5] = (_Float16)(OMEGA * wb.y);
            h[6] = (_Float16)(OMEGA * wb.z); h[7] = (_Float16)(OMEGA * wb.w);
            AT4[b][mt][lane] = h;
        }
        if (tid < 64) {
            w0tab[tid] = make_float4(OMEGA * W0[2 * tid], OMEGA * W0[2 * tid + 1],
                                     OMEGA * b0[tid], 0.f);
            btab[0][tid] = OMEGA * b1[tid];
            btab[1][tid] = OMEGA * b2[tid];
            btab[2][tid] = OMEGA * b3[tid];
        }
        if (tid < 128) b4tab[tid] = OMEGA * b4[tid];
    }
    __syncthreads();

    // ---------------- main loop: one wave = 16 points per batch ----------------
    const int p   = lane & 15;                // point-in-batch (= MFMA column)
    const int sr  = lane >> 5;                // store-side row parity (0/1)
    const int sc  = lane & 31;                // store-side float4 chunk 0..31
    const int nb  = (n + 15) >> 4;
    const int wv  = blockIdx.x * 4 + w;
    const int nw  = gridDim.x * 4;

    for (int batch = wv; batch < nb; batch += nw) {
        int point = batch * 16 + p;
        int pt    = point < n ? point : n - 1;
        float2 c2 = *(const float2*)(coords + 2ull * (unsigned)pt);

        // Layer 0 (fp32 VALU): lane computes Z0[nrn][p] for nrn = 16t+4g+r,
        // landing directly in B-fragment slots: zb[t>>1][4*(t&1)+r].
        half8 zb[2];
        #pragma unroll
        for (int t = 0; t < 4; ++t) {
            #pragma unroll
            for (int r = 0; r < 4; ++r) {
                float4 ww = w0tab[16 * t + 4 * g + r];
                float z = __sinf(fmaf(c2.x, ww.x, fmaf(c2.y, ww.y, ww.z)));
                zb[t >> 1][4 * (t & 1) + r] = (_Float16)z;
            }
        }

        // Hidden layers 1..3
        #pragma unroll
        for (int L = 0; L < 3; ++L) {
            f32x4 acc[4];
            #pragma unroll
            for (int t = 0; t < 4; ++t) {
                float4 bv = *(const float4*)&btab[L][16 * t + 4 * g];
                acc[t][0] = bv.x; acc[t][1] = bv.y; acc[t][2] = bv.z; acc[t][3] = bv.w;
            }
            #pragma unroll
            for (int b = 0; b < 2; ++b) {
                #pragma unroll
                for (int mt = 0; mt < 4; ++mt) {
                    acc[mt] = __builtin_amdgcn_mfma_f32_16x16x32_f16(
                        AT[L][b][mt][lane], zb[b], acc[mt], 0, 0, 0);
                }
            }
            // activation + repack: D-regs -> next B-frags, all in-lane
            half8 zn[2];
            #pragma unroll
            for (int t = 0; t < 4; ++t) {
                #pragma unroll
                for (int r = 0; r < 4; ++r) {
                    zn[t >> 1][4 * (t & 1) + r] = (_Float16)__sinf(acc[t][r]);
                }
            }
            zb[0] = zn[0]; zb[1] = zn[1];
        }

        // Output layer: 64 -> 128, all 8 mt-tiles into the per-wave LDS slab
        // (chunk-XOR swizzle), then 8 fully-contiguous 1 KB bypass stores.
        #pragma unroll
        for (int mt = 0; mt < 8; ++mt) {
            float4 bv = *(const float4*)&b4tab[16 * mt + 4 * g];
            f32x4 a4;
            a4[0] = bv.x; a4[1] = bv.y; a4[2] = bv.z; a4[3] = bv.w;
            a4 = __builtin_amdgcn_mfma_f32_16x16x32_f16(AT4[0][mt][lane], zb[0], a4, 0, 0, 0);
            a4 = __builtin_amdgcn_mfma_f32_16x16x32_f16(AT4[1][mt][lane], zb[1], a4, 0, 0, 0);
            f32x4 o;
            o[0] = __sinf(a4[0]); o[1] = __sinf(a4[1]);
            o[2] = __sinf(a4[2]); o[3] = __sinf(a4[3]);
            int chunk = (4 * mt + g) ^ (p & 7);      // float4-chunk swizzle
            *(f32x4*)&stage[w][p][4 * chunk] = o;
        }
        // Store: instruction i writes point rows 2i (lanes 0-31) and 2i+1
        // (lanes 32-63) -- 1 KB contiguous per instruction.
        // sc1 nt: DEVICE-scope streaming store. Coherence point below the
        // per-XCD L2 -> still bypasses the L2 RFO (r7 mechanism), but may
        // ride the faster MALL write path instead of system/HBM-direct.
        const float* sbase = &stage[w][0][0];
        #pragma unroll
        for (int i = 0; i < 8; ++i) {
            int row = 2 * i + sr;
            int cs  = sc ^ (row & 7);
            f32x4 o4 = *(const f32x4*)(sbase + 128 * row + 4 * cs);
            int pointp = batch * 16 + row;
            if (pointp < n) {
                float* gp = out + (size_t)pointp * 128 + 4 * sc;
                asm volatile("global_store_dwordx4 %0, %1, off sc1 nt"
                             :: "v"(gp), "v"(o4) : "memory");
            }
        }
    }
}

extern "C" void kernel_launch(void* const* d_in, const int* in_sizes, int n_in,
                              void* d_out, int out_size, void* d_ws, size_t ws_size,
                              hipStream_t stream) {
    const float* coords = (const float*)d_in[0];
    const float* W0 = (const float*)d_in[1];
    const float* b0 = (const float*)d_in[2];
    const float* W1 = (const float*)d_in[3];
    const float* b1 = (const float*)d_in[4];
    const float* W2 = (const float*)d_in[5];
    const float* b2 = (const float*)d_in[6];
    const float* W3 = (const float*)d_in[7];
    const float* b3 = (const float*)d_in[8];
    const float* W4 = (const float*)d_in[9];
    const float* b4 = (const float*)d_in[10];
    float* out = (float*)d_out;

    int n = in_sizes[0] / 2;  // coords is (N, 2)
    int nb = (n + 15) / 16;
    int blocks = 512;         // 2 blocks/CU (74.5 KB LDS), 4 waves each
    int maxb = (nb + 3) / 4;
    if (blocks > maxb) blocks = maxb;
    hipLaunchKernelGGL(siren_mfma_kernel, dim3(blocks), dim3(256), 0, stream,
                       coords, W0, b0, W1, b1, W2, b2, W3, b3, W4, b4, out, n);
}

// Round 15
// 117.479 us; speedup vs baseline: 1.1966x; 1.0552x over previous
//
#include <hip/hip_runtime.h>

// SIREN forward, MFMA, round 15: minimal-diff occupancy probe from r7.
//
// Ladder: 1526 -> 473 -> 326 -> 122.5 us (r7 champion: 1KB-contiguous
// sc0 sc1 nt stores kill the L2 store-miss read-fill). r8 weights->VGPR:
// neutral (VGPR-limited to same 8 waves/CU). r10 64B pieces: -15%.
// r12 device==system scope. r9/r11/r13/r14: all-zeros failures on
// multi-axis structural edits (cause never isolated).
//
// This round changes exactly ONE structural variable vs r7: the f32 stage
// shrinks [4][16][128] -> [4][16][32] (32 KB -> 8 KB), epilogue runs as
// 4 passes of {2 mt-tiles MFMA+sin -> slab -> 2 store instrs}. Types,
// store instruction (sc0 sc1 nt dwordx4), swizzle family, prep, layers:
// byte-identical to r7. LDS 74.5 -> 50.25 KB => 3 blocks/CU = 12 waves/CU
// at VGPR=128 (4/SIMD allowed; LDS now binding at 3). Grid 512 -> 768.
// Store instrs cover 8 rows x 128 B pieces (contiguity-threshold probe;
// r10 showed 64 B costs 15%, 1 KB is best known).

typedef _Float16 half8 __attribute__((ext_vector_type(8)));
typedef float f32x4 __attribute__((ext_vector_type(4)));

#define OMEGA 5.0f

__global__ __launch_bounds__(256, 2) void siren_mfma_kernel(
    const float* __restrict__ coords,
    const float* __restrict__ W0, const float* __restrict__ b0,
    const float* __restrict__ W1, const float* __restrict__ b1,
    const float* __restrict__ W2, const float* __restrict__ b2,
    const float* __restrict__ W3, const float* __restrict__ b3,
    const float* __restrict__ W4, const float* __restrict__ b4,
    float* __restrict__ out, int n)
{
    // Pre-gathered A-fragment tables: [kblock][mtile][lane] -> 8 f16 (16 B).
    __shared__ half8 AT[3][2][4][64];    // hidden layers W1..W3: 24 KB
    __shared__ half8 AT4[2][8][64];      // W4: 16 KB
    __shared__ float4 w0tab[64];         // {5*W0[n][0], 5*W0[n][1], 5*b0[n], 0}
    __shared__ __align__(16) float btab[3][64];   // 5*b1..b3
    __shared__ __align__(16) float b4tab[128];    // 5*b4
    // Per-wave output slab: 16 points x 32 cols f32 (2 KB/wave, 8 KB).
    // float4-chunk XOR swizzle (3-bit: qc = c ^ (p&7)), bijective per row.
    __shared__ float stage[4][16][32];

    const int tid  = threadIdx.x;
    const int lane = tid & 63;
    const int g    = lane >> 4;        // lane group 0..3
    const int w    = tid >> 6;         // wave in block

    // ---------------- prep: build fragment tables (r7-identical) ----------------
    {
        const float* Wp[3] = {W1, W2, W3};
        #pragma unroll
        for (int L = 0; L < 3; ++L) {
            #pragma unroll
            for (int c = 0; c < 2; ++c) {
                int chunk = w + 4 * c;               // 0..7 = b*4 + mt
                int b  = chunk >> 2, mt = chunk & 3;
                const float* src = Wp[L] + (16 * mt + (lane & 15)) * 64 + 32 * b + 4 * g;
                float4 wa = *(const float4*)(src);
                float4 wb = *(const float4*)(src + 16);
                half8 h;
                h[0] = (_Float16)(OMEGA * wa.x); h[1] = (_Float16)(OMEGA * wa.y);
                h[2] = (_Float16)(OMEGA * wa.z); h[3] = (_Float16)(OMEGA * wa.w);
                h[4] = (_Float16)(OMEGA * wb.x); h[5] = (_Float16)(OMEGA * wb.y);
                h[6] = (_Float16)(OMEGA * wb.z); h[7] = (_Float16)(OMEGA * wb.w);
                AT[L][b][mt][lane] = h;
            }
        }
        #pragma unroll
        for (int c = 0; c < 4; ++c) {
            int chunk = w + 4 * c;                   // 0..15 = b*8 + mt
            int b  = chunk >> 3, mt = chunk & 7;
            const float* src = W4 + (16 * mt + (lane & 15)) * 64 + 32 * b + 4 * g;
            float4 wa = *(const float4*)(src);
            float4 wb = *(const float4*)(src + 16);
            half8 h;
            h[0] = (_Float16)(OMEGA * wa.x); h[1] = (_Float16)(OMEGA * wa.y);
            h[2] = (_Float16)(OMEGA * wa.z); h[3] = (_Float16)(OMEGA * wa.w);
            h[4] = (_Float16)(OMEGA * wb.x); h[5] = (_Float16)(OMEGA * wb.y);
            h[6] = (_Float16)(OMEGA * wb.z); h[7] = (_Float16)(OMEGA * wb.w);
            AT4[b][mt][lane] = h;
        }
        if (tid < 64) {
            w0tab[tid] = make_float4(OMEGA * W0[2 * tid], OMEGA * W0[2 * tid + 1],
                                     OMEGA * b0[tid], 0.f);
            btab[0][tid] = OMEGA * b1[tid];
            btab[1][tid] = OMEGA * b2[tid];
            btab[2][tid] = OMEGA * b3[tid];
        }
        if (tid < 128) b4tab[tid] = OMEGA * b4[tid];
    }
    __syncthreads();

    // ---------------- main loop: one wave = 16 points per batch ----------------
    const int p   = lane & 15;                // point-in-batch (= MFMA column)
    const int sr8 = lane >> 3;                // store-side row-in-octet (0..7)
    const int q3  = lane & 7;                 // store-side float4 chunk 0..7
    const int nb  = (n + 15) >> 4;
    const int wv  = blockIdx.x * 4 + w;
    const int nw  = gridDim.x * 4;

    for (int batch = wv; batch < nb; batch += nw) {
        int point = batch * 16 + p;
        int pt    = point < n ? point : n - 1;
        float2 c2 = *(const float2*)(coords + 2ull * (unsigned)pt);

        // Layer 0 (fp32 VALU): lane computes Z0[nrn][p] for nrn = 16t+4g+r,
        // landing directly in B-fragment slots: zb[t>>1][4*(t&1)+r].
        half8 zb[2];
        #pragma unroll
        for (int t = 0; t < 4; ++t) {
            #pragma unroll
            for (int r = 0; r < 4; ++r) {
                float4 ww = w0tab[16 * t + 4 * g + r];
                float z = __sinf(fmaf(c2.x, ww.x, fmaf(c2.y, ww.y, ww.z)));
                zb[t >> 1][4 * (t & 1) + r] = (_Float16)z;
            }
        }

        // Hidden layers 1..3
        #pragma unroll
        for (int L = 0; L < 3; ++L) {
            f32x4 acc[4];
            #pragma unroll
            for (int t = 0; t < 4; ++t) {
                float4 bv = *(const float4*)&btab[L][16 * t + 4 * g];
                acc[t][0] = bv.x; acc[t][1] = bv.y; acc[t][2] = bv.z; acc[t][3] = bv.w;
            }
            #pragma unroll
            for (int b = 0; b < 2; ++b) {
                #pragma unroll
                for (int mt = 0; mt < 4; ++mt) {
                    acc[mt] = __builtin_amdgcn_mfma_f32_16x16x32_f16(
                        AT[L][b][mt][lane], zb[b], acc[mt], 0, 0, 0);
                }
            }
            // activation + repack: D-regs -> next B-frags, all in-lane
            half8 zn[2];
            #pragma unroll
            for (int t = 0; t < 4; ++t) {
                #pragma unroll
                for (int r = 0; r < 4; ++r) {
                    zn[t >> 1][4 * (t & 1) + r] = (_Float16)__sinf(acc[t][r]);
                }
            }
            zb[0] = zn[0]; zb[1] = zn[1];
        }

        // Output layer: 64 -> 128 in FOUR 32-col passes. Each pass: 2
        // mt-tiles MFMA+sin -> f32 slab (3-bit chunk XOR swizzle) -> 2 store
        // instructions (rows {8i..8i+7} x 128 B pieces), sc0 sc1 nt bypass.
        #pragma unroll
        for (int P = 0; P < 4; ++P) {
            #pragma unroll
            for (int m = 0; m < 2; ++m) {
                int mt = 2 * P + m;
                float4 bv = *(const float4*)&b4tab[16 * mt + 4 * g];
                f32x4 a4;
                a4[0] = bv.x; a4[1] = bv.y; a4[2] = bv.z; a4[3] = bv.w;
                a4 = __builtin_amdgcn_mfma_f32_16x16x32_f16(AT4[0][mt][lane], zb[0], a4, 0, 0, 0);
                a4 = __builtin_amdgcn_mfma_f32_16x16x32_f16(AT4[1][mt][lane], zb[1], a4, 0, 0, 0);
                f32x4 o;
                o[0] = __sinf(a4[0]); o[1] = __sinf(a4[1]);
                o[2] = __sinf(a4[2]); o[3] = __sinf(a4[3]);
                int qc = (2 * m + g) & 7;            // wait -- see below
                // local chunk within pass = 4*m+g? No: cols 16m+4g+r ->
                // chunk c = 4m+g for m in 0..1 => c in 0..7. 3-bit swizzle:
                qc = (4 * m + g) ^ (p & 7);
                *(f32x4*)&stage[w][p][4 * qc] = o;
            }
            // Store pass: instruction i covers rows {8i..8i+7}, lane
            // (sr8, q3): row 8i+sr8, f32 cols 4*q3..4*q3+3 of this pass.
            #pragma unroll
            for (int i = 0; i < 2; ++i) {
                int row = 8 * i + sr8;
                int sq  = q3 ^ (row & 7);            // matching 3-bit swizzle
                f32x4 o4 = *(const f32x4*)&stage[w][row][4 * sq];
                int pointp = batch * 16 + row;
                if (pointp < n) {
                    float* gp = out + (size_t)pointp * 128 + 32 * P + 4 * q3;
                    asm volatile("global_store_dwordx4 %0, %1, off sc0 sc1 nt"
                                 :: "v"(gp), "v"(o4) : "memory");
                }
            }
        }
    }
}

extern "C" void kernel_launch(void* const* d_in, const int* in_sizes, int n_in,
                              void* d_out, int out_size, void* d_ws, size_t ws_size,
                              hipStream_t stream) {
    const float* coords = (const float*)d_in[0];
    const float* W0 = (const float*)d_in[1];
    const float* b0 = (const float*)d_in[2];
    const float* W1 = (const float*)d_in[3];
    const float* b1 = (const float*)d_in[4];
    const float* W2 = (const float*)d_in[5];
    const float* b2 = (const float*)d_in[6];
    const float* W3 = (const float*)d_in[7];
    const float* b3 = (const float*)d_in[8];
    const float* W4 = (const float*)d_in[9];
    const float* b4 = (const float*)d_in[10];
    float* out = (float*)d_out;

    int n = in_sizes[0] / 2;  // coords is (N, 2)
    int nb = (n + 15) / 16;
    int blocks = 768;         // 3 blocks/CU (50.25 KB LDS), 4 waves each
    int maxb = (nb + 3) / 4;
    if (blocks > maxb) blocks = maxb;
    hipLaunchKernelGGL(siren_mfma_kernel, dim3(blocks), dim3(256), 0, stream,
                       coords, W0, b0, W1, b1, W2, b2, W3, b3, W4, b4, out, n);
}